// Round 1
// baseline (668.692 us; speedup 1.0000x reference)
//
#include <hip/hip_runtime.h>
#include <math.h>

typedef unsigned long long u64;
typedef unsigned int u32;

#define M_CAND 6960
#define MW 112        // mask row stride in u64 words (109 used, padded to 112)
#define NW 109
#define NSORT 8192
#define KSEL 4096

// ws layout (bytes)
#define OFF_BOX   0u          // float4 [2][6960]
#define OFF_SBOX  222720u     // float4 [2][6960]
#define OFF_CS    445440u     // float  [2][6960]
#define OFF_CP    501120u     // u32    [2][6960]
#define OFF_SS    556800u     // float  [2][6960]
#define OFF_KEY   612480u     // u64    [2][8192]
#define OFF_MASK  743552u     // u64    [2][6960][112]

__device__ __forceinline__ u32 fmono(float f) {
  u32 u = __float_as_uint(f);
  return (u & 0x80000000u) ? ~u : (u | 0x80000000u);
}
__device__ __forceinline__ float fmono_inv(u32 m) {
  u32 u = (m & 0x80000000u) ? (m & 0x7FFFFFFFu) : ~m;
  return __uint_as_float(u);
}

struct Ptrs { const float* cls[5]; const float* reg[5]; const int* ih; const int* iw; };

__device__ const int d_dims[5]    = {128, 64, 32, 16, 8};
__device__ const int d_strides[5] = {8, 16, 32, 64, 128};
__device__ const int d_kvals[5]   = {2000, 2000, 2000, 768, 192};
__device__ const int d_segoff[5]  = {0, 2000, 4000, 6000, 6768};

// ---------------- kernel 1: per-level sigmoid + top-k selection ----------------
__global__ __launch_bounds__(1024) void k_select(Ptrs P, float* cand_score, u32* cand_pos) {
  const int lvl = blockIdx.x % 5, img = blockIdx.x / 5;
  const int W = d_dims[lvl], HW = W * W, n = HW * 3, k = d_kvals[lvl], off = d_segoff[lvl];
  const float* cls = P.cls[lvl] + (size_t)img * 3 * HW;
  float* cs = cand_score + img * M_CAND + off;
  u32*   cp = cand_pos   + img * M_CAND + off;
  const int tid = threadIdx.x;

  if (n <= k) {
    for (int e = tid; e < n; e += blockDim.x) {
      int a = e / HW, hw = e - a * HW;
      float s = 1.0f / (1.0f + expf(-cls[e]));
      cs[e] = s;
      cp[e] = ((u32)lvl << 20) | (u32)(hw * 3 + a);
    }
    return;
  }

  __shared__ u32 hist[2048];
  __shared__ u64 list[KSEL];
  __shared__ int s_T, s_cnt;
  for (int b = tid; b < 2048; b += blockDim.x) hist[b] = 0;
  if (tid == 0) s_cnt = 0;
  __syncthreads();
  for (int e = tid; e < n; e += blockDim.x) {
    float s = 1.0f / (1.0f + expf(-cls[e]));
    int bk = (int)(s * 2048.0f);
    bk = bk > 2047 ? 2047 : bk;
    atomicAdd(&hist[bk], 1u);
  }
  __syncthreads();
  if (tid == 0) {
    int acc = 0, T = 0;
    for (int b = 2047; b >= 0; --b) { acc += (int)hist[b]; if (acc >= k) { T = b; break; } }
    s_T = T;
  }
  __syncthreads();
  const int T = s_T;
  for (int e = tid; e < n; e += blockDim.x) {
    float s = 1.0f / (1.0f + expf(-cls[e]));
    int bk = (int)(s * 2048.0f);
    bk = bk > 2047 ? 2047 : bk;
    if (bk >= T) {
      int p = atomicAdd(&s_cnt, 1);
      if (p < KSEL) {
        int a = e / HW, hw = e - a * HW;
        u32 i = (u32)(hw * 3 + a);
        list[p] = ~(((u64)fmono(s) << 32) | (u32)(~i));   // store inverted key; ascending sort == score desc
      }
    }
  }
  __syncthreads();
  int cnt = s_cnt; if (cnt > KSEL) cnt = KSEL;
  for (int p = tid; p < KSEL; p += blockDim.x) if (p >= cnt) list[p] = ~0ull;
  // bitonic ascending sort of inverted keys
  for (u32 kk = 2; kk <= KSEL; kk <<= 1)
    for (u32 j = kk >> 1; j > 0; j >>= 1) {
      __syncthreads();
      for (int e = 0; e < KSEL / 1024; ++e) {
        u32 idx = (u32)tid + (u32)(e * 1024);
        u32 pr = idx ^ j;
        if (pr > idx) {
          u64 a = list[idx], b = list[pr];
          bool up = ((idx & kk) == 0);
          if ((a > b) == up) { list[idx] = b; list[pr] = a; }
        }
      }
    }
  __syncthreads();
  for (int t = tid; t < k; t += blockDim.x) {
    u64 key = ~list[t];
    cs[t] = fmono_inv((u32)(key >> 32));
    u32 i = ~(u32)key;
    cp[t] = ((u32)lvl << 20) | (i & 0xFFFFFu);
  }
}

// ---------------- kernel 2: decode boxes + build sort keys ----------------
__global__ void k_decode(Ptrs P, const float* cand_score, const u32* cand_pos,
                         float4* boxes, u64* keys) {
#pragma clang fp contract(off)
  int t = blockIdx.x * blockDim.x + threadIdx.x;
  if (t >= 2 * NSORT) return;
  int img = t >> 13, slot = t & (NSORT - 1);
  u64* key = keys + (size_t)img * NSORT;
  if (slot >= M_CAND) { key[slot] = 0ull; return; }
  float s = cand_score[img * M_CAND + slot];
  u32 pc = cand_pos[img * M_CAND + slot];
  int lvl = (int)(pc >> 20), idx = (int)(pc & 0xFFFFFu);
  int W = d_dims[lvl], HW = W * W, stride = d_strides[lvl];
  int a = idx % 3, cell = idx / 3;
  int wx = cell % W, hy = cell / W;
  // anchors, numpy-identical fp32 op order
  const float rr[3] = {0.5f, 1.0f, 2.0f};
  float sw = (float)(stride * 8);
  float wsz = sw * sqrtf(1.0f / rr[a]);
  float hsz = sw * sqrtf(rr[a]);
  float ax = (float)(wx * stride), ay = (float)(hy * stride);
  float a0 = ax + (-(wsz * 0.5f));
  float a1 = ay + (-(hsz * 0.5f));
  float a2 = ax + (wsz * 0.5f);
  float a3 = ay + (hsz * 0.5f);
  const float* rg = P.reg[lvl] + ((size_t)img * 12 + (size_t)(a * 4)) * HW + (size_t)hy * W + wx;
  float dx = rg[0], dy = rg[HW], dw = rg[2 * HW], dh = rg[3 * HW];
  const float MR = 4.135166556742356f;
  dw = fminf(fmaxf(dw, -MR), MR);
  dh = fminf(fmaxf(dh, -MR), MR);
  float px = (a0 + a2) * 0.5f, py = (a1 + a3) * 0.5f;
  float pw = a2 - a0, ph = a3 - a1;
  float gx = px + pw * dx;
  float gy = py + ph * dy;
  float gw = pw * expf(dw);
  float gh = ph * expf(dh);
  float fw = (float)(*P.iw), fh = (float)(*P.ih);
  float x1 = fminf(fmaxf(gx - gw * 0.5f, 0.0f), fw);
  float y1 = fminf(fmaxf(gy - gh * 0.5f, 0.0f), fh);
  float x2 = fminf(fmaxf(gx + gw * 0.5f, 0.0f), fw);
  float y2 = fminf(fmaxf(gy + gh * 0.5f, 0.0f), fh);
  boxes[(size_t)img * M_CAND + slot] = make_float4(x1, y1, x2, y2);
  if (!((x2 - x1 > 0.0f) && (y2 - y1 > 0.0f))) s = -1.0f;
  key[slot] = ((u64)fmono(s) << 32) | (u32)(~(u32)slot);
}

// ---------------- kernel 3: per-image global sort (bitonic 8192 in LDS) ----------------
__global__ __launch_bounds__(1024) void k_sort(const u64* keys, const float4* boxes,
                                               float4* sboxes, float* sscore) {
  __shared__ u64 lds[NSORT];   // 64 KB
  const int img = blockIdx.x, tid = threadIdx.x;
  const u64* kin = keys + (size_t)img * NSORT;
  for (int t2 = tid; t2 < NSORT; t2 += 1024) lds[t2] = ~kin[t2];
  for (u32 kk = 2; kk <= NSORT; kk <<= 1)
    for (u32 j = kk >> 1; j > 0; j >>= 1) {
      __syncthreads();
      for (int e = 0; e < NSORT / 1024; ++e) {
        u32 idx = (u32)tid + (u32)(e * 1024);
        u32 pr = idx ^ j;
        if (pr > idx) {
          u64 a = lds[idx], b = lds[pr];
          bool up = ((idx & kk) == 0);
          if ((a > b) == up) { lds[idx] = b; lds[pr] = a; }
        }
      }
    }
  __syncthreads();
  for (int t2 = tid; t2 < M_CAND; t2 += 1024) {
    u64 key = ~lds[t2];
    u32 orig = ~(u32)key;
    sscore[(size_t)img * M_CAND + t2] = fmono_inv((u32)(key >> 32));
    sboxes[(size_t)img * M_CAND + t2] = boxes[(size_t)img * M_CAND + orig];
  }
}

// ---------------- kernel 4: suppression bitmask ----------------
__global__ __launch_bounds__(256) void k_mask(const float4* sboxes, u64* mask) {
#pragma clang fp contract(off)
  const int img = blockIdx.x / NW;
  const int rg = blockIdx.x % NW;
  const int tid = threadIdx.x;
  const int r = tid >> 2, q = tid & 3;
  const int i = (rg << 6) + r;
  const float4* BB = sboxes + (size_t)img * M_CAND;
  float4 bi = make_float4(0.f, 0.f, 0.f, 0.f);
  if (i < M_CAND) bi = BB[i];
  float areaI = (bi.z - bi.x) * (bi.w - bi.y);
  __shared__ float4 tj[256];
  __shared__ float ta[256];
  const int ntiles = (M_CAND + 255) >> 8;  // 28
  for (int jt = rg >> 2; jt < ntiles; ++jt) {
    __syncthreads();
    int j0 = (jt << 8) + tid;
    float4 bj = make_float4(0.f, 0.f, 0.f, 0.f);
    if (j0 < M_CAND) bj = BB[j0];
    tj[tid] = bj;
    ta[tid] = (bj.z - bj.x) * (bj.w - bj.y);
    __syncthreads();
    if (i < M_CAND) {
      u64 bits = 0ull;
      int jbase = (jt << 8) + (q << 6);
      for (int b = 0; b < 64; ++b) {
        float4 bb = tj[(q << 6) + b];
        float aj = ta[(q << 6) + b];
        float ltx = fmaxf(bi.x, bb.x), lty = fmaxf(bi.y, bb.y);
        float rbx = fminf(bi.z, bb.z), rby = fminf(bi.w, bb.w);
        float ww = fmaxf(rbx - ltx, 0.0f), hh = fmaxf(rby - lty, 0.0f);
        float inter = ww * hh;
        float uni = (areaI + aj) - inter;
        float iou = inter / fmaxf(uni, 1e-9f);
        int j = jbase + b;
        bits |= ((u64)(iou > 0.7f && j > i && j < M_CAND)) << b;
      }
      mask[((size_t)img * M_CAND + i) * MW + (size_t)((jt << 2) + q)] = bits;
    }
  }
}

// ---------------- kernel 5: sequential greedy NMS scan + output ----------------
__global__ __launch_bounds__(64) void k_scan(const float4* sboxes, const float* sscore,
                                             const u64* mask, float* out) {
  const int img = blockIdx.x;
  const int L = threadIdx.x;
  const float4* BB = sboxes + (size_t)img * M_CAND;
  const float* SS = sscore + (size_t)img * M_CAND;
  const u64* MK = mask + (size_t)img * M_CAND * MW;
  u64 r0 = 0ull, r1 = 0ull;   // removed words: lane L owns word L and word L+64
  int total = 0;
  const int G = (M_CAND + 63) >> 6;  // 109
  for (int g = 0; g < G; ++g) {
    int i = (g << 6) + L;
    float si = (i < M_CAND) ? SS[i] : -1.0f;
    u64 validm = __ballot(si > 0.0f);
    if (validm == 0ull) break;                       // sorted desc: nothing valid after
    u64 cur = (g < 64) ? __shfl(r0, g) : __shfl(r1, g - 64);
    u64 rem = cur | ~validm;
    if (rem == ~0ull) continue;
    u64 myword = (i < M_CAND) ? MK[(size_t)i * MW + g] : 0ull;
    u64 keptm = 0ull;
    for (int l = 0; l < 64; ++l) {
      if (!((rem >> l) & 1ull)) {
        keptm |= (1ull << l);
        rem |= __shfl(myword, l);
      }
    }
    bool kept = (keptm >> L) & 1ull;
    int pos = total + __popcll(keptm & ((1ull << L) - 1ull));
    if (kept && pos < 1000) {
      float4 bx = BB[i];
      float* ob = out + ((size_t)img * 1000 + pos) * 4;
      ob[0] = bx.x; ob[1] = bx.y; ob[2] = bx.z; ob[3] = bx.w;
      out[8000 + img * 1000 + pos] = si;
      out[12000 + img * 1000 + pos] = 1.0f;
    }
    total += __popcll(keptm);
    if (total >= 1000) break;
    if (g == G - 1) break;
    // OR kept rows into the distributed removed vector (4-wide batched, coalesced)
    const bool okL = (L >= g);
    const bool okH = (L + 64 <= 111);
    u64 km = keptm;
    while (km) {
      int l0 = __ffsll(km) - 1; km &= km - 1;
      int l1 = -1, l2 = -1, l3 = -1;
      if (km) { l1 = __ffsll(km) - 1; km &= km - 1; }
      if (km) { l2 = __ffsll(km) - 1; km &= km - 1; }
      if (km) { l3 = __ffsll(km) - 1; km &= km - 1; }
      const u64* w0 = MK + (size_t)((g << 6) + l0) * MW;
      u64 A0 = okL ? w0[L] : 0ull, B0 = okH ? w0[L + 64] : 0ull;
      u64 A1 = 0, B1 = 0, A2 = 0, B2 = 0, A3 = 0, B3 = 0;
      if (l1 >= 0) { const u64* w = MK + (size_t)((g << 6) + l1) * MW; A1 = okL ? w[L] : 0ull; B1 = okH ? w[L + 64] : 0ull; }
      if (l2 >= 0) { const u64* w = MK + (size_t)((g << 6) + l2) * MW; A2 = okL ? w[L] : 0ull; B2 = okH ? w[L + 64] : 0ull; }
      if (l3 >= 0) { const u64* w = MK + (size_t)((g << 6) + l3) * MW; A3 = okL ? w[L] : 0ull; B3 = okH ? w[L + 64] : 0ull; }
      r0 |= A0 | A1 | A2 | A3;
      r1 |= B0 | B1 | B2 | B3;
    }
  }
  // pad remaining output slots
  int filled = total < 1000 ? total : 1000;
  for (int p = filled + L; p < 1000; p += 64) {
    float* ob = out + ((size_t)img * 1000 + p) * 4;
    ob[0] = 0.0f; ob[1] = 0.0f; ob[2] = 0.0f; ob[3] = 0.0f;
    out[8000 + img * 1000 + p] = 0.0f;
    out[12000 + img * 1000 + p] = 0.0f;
  }
  for (int p = L; p < 1000; p += 64) out[10000 + img * 1000 + p] = 0.0f;  // labels
}

extern "C" void kernel_launch(void* const* d_in, const int* in_sizes, int n_in,
                              void* d_out, int out_size, void* d_ws, size_t ws_size,
                              hipStream_t stream) {
  Ptrs P;
  for (int i = 0; i < 5; ++i) {
    P.cls[i] = (const float*)d_in[2 * i];
    P.reg[i] = (const float*)d_in[2 * i + 1];
  }
  P.ih = (const int*)d_in[10];
  P.iw = (const int*)d_in[11];

  char* w = (char*)d_ws;
  float4* boxes  = (float4*)(w + OFF_BOX);
  float4* sboxes = (float4*)(w + OFF_SBOX);
  float*  cscore = (float*)(w + OFF_CS);
  u32*    cpos   = (u32*)(w + OFF_CP);
  float*  sscore = (float*)(w + OFF_SS);
  u64*    keys   = (u64*)(w + OFF_KEY);
  u64*    maskp  = (u64*)(w + OFF_MASK);
  float* out = (float*)d_out;

  hipLaunchKernelGGL(k_select, dim3(10), dim3(1024), 0, stream, P, cscore, cpos);
  hipLaunchKernelGGL(k_decode, dim3((2 * NSORT) / 256), dim3(256), 0, stream, P, cscore, cpos, boxes, keys);
  hipLaunchKernelGGL(k_sort, dim3(2), dim3(1024), 0, stream, keys, boxes, sboxes, sscore);
  hipLaunchKernelGGL(k_mask, dim3(2 * NW), dim3(256), 0, stream, sboxes, maskp);
  hipLaunchKernelGGL(k_scan, dim3(2), dim3(64), 0, stream, sboxes, sscore, maskp, out);
}

// Round 2
// 606.200 us; speedup vs baseline: 1.1031x; 1.1031x over previous
//
#include <hip/hip_runtime.h>
#include <math.h>

typedef unsigned long long u64;
typedef unsigned int u32;

#define M_CAND 6960
#define MW 112        // mask row stride in u64 words (109 used, padded to 112)
#define NW 109
#define CAP 4096      // k_select candidate capacity

// ws layout (bytes)
#define OFF_BOX   0u          // float4 [2][6960]
#define OFF_SBOX  222720u     // float4 [2][6960]
#define OFF_CS    445440u     // float  [2][6960]
#define OFF_CP    501120u     // u32    [2][6960]
#define OFF_SS    528960u     // float  [2][6960]
#define OFF_KEY   584640u     // u64    [2][6960]
#define OFF_MASK  696000u     // u64    [2][6960][112]

__device__ __forceinline__ u32 fmono(float f) {
  u32 u = __float_as_uint(f);
  return (u & 0x80000000u) ? ~u : (u | 0x80000000u);
}
__device__ __forceinline__ float fmono_inv(u32 m) {
  u32 u = (m & 0x80000000u) ? (m & 0x7FFFFFFFu) : ~m;
  return __uint_as_float(u);
}
__device__ __forceinline__ u64 readlane64(u64 v, int l) {
  u32 lo = (u32)__builtin_amdgcn_readlane((int)(u32)v, l);
  u32 hi = (u32)__builtin_amdgcn_readlane((int)(u32)(v >> 32), l);
  return ((u64)hi << 32) | lo;
}

struct Ptrs { const float* cls[5]; const float* reg[5]; const int* ih; const int* iw; };

__device__ const int d_dims[5]    = {128, 64, 32, 16, 8};
__device__ const int d_strides[5] = {8, 16, 32, 64, 128};
__device__ const int d_kvals[5]   = {2000, 2000, 2000, 768, 192};
__device__ const int d_segoff[5]  = {0, 2000, 4000, 6000, 6768};

// ---------------- kernel 1: per-level sigmoid + exact top-k via ranking ----------------
__global__ __launch_bounds__(1024) void k_select(Ptrs P, float* cand_score, u32* cand_pos) {
  const int lvl = blockIdx.x % 5, img = blockIdx.x / 5;
  const int W = d_dims[lvl], HW = W * W, n = HW * 3, k = d_kvals[lvl], off = d_segoff[lvl];
  const float* cls = P.cls[lvl] + (size_t)img * 3 * HW;
  float* cs = cand_score + img * M_CAND + off;
  u32*   cp = cand_pos   + img * M_CAND + off;
  const int tid = threadIdx.x;

  __shared__ u32 hist[2048];
  __shared__ u64 keys[CAP];    // 32 KB
  __shared__ int s_T, s_cnt;

  int T = 0;
  if (n > k) {
    for (int b = tid; b < 2048; b += 1024) hist[b] = 0;
    __syncthreads();
    for (int e = tid; e < n; e += 1024) {
      float s = 1.0f / (1.0f + expf(-cls[e]));
      int bk = (int)(s * 2048.0f); bk = bk > 2047 ? 2047 : bk;
      atomicAdd(&hist[bk], 1u);
    }
    __syncthreads();
    // threshold: wave-parallel suffix over 64 superbins of 32 bins
    if (tid < 64) {
      u32 part = 0;
      for (int j = 0; j < 32; ++j) part += hist[tid * 32 + ((j + tid) & 31)];  // swizzle: conflict-free
      u32 ss = part;
      for (int d = 1; d < 64; d <<= 1) {
        u32 o = __shfl_down(ss, d);
        if (tid + d < 64) ss += o;    // ss = inclusive suffix sum of superbin counts
      }
      u64 m = __ballot(ss >= (u32)k);
      int SB = 63 - __clzll(m);       // highest superbin whose suffix >= k
      if (tid == SB) {
        u32 acc = ss - part;          // count above this superbin
        int Tloc = SB * 32;
        for (int b = SB * 32 + 31; b >= SB * 32; --b) {
          acc += hist[b];
          if (acc >= (u32)k) { Tloc = b; break; }
        }
        s_T = Tloc;
      }
    }
    __syncthreads();
    T = s_T;
  }
  if (tid == 0) s_cnt = 0;
  __syncthreads();
  // compact candidates (bucket >= T) into LDS
  for (int e = tid; e < n; e += 1024) {
    float s = 1.0f / (1.0f + expf(-cls[e]));
    bool sel = true;
    if (n > k) {
      int bk = (int)(s * 2048.0f); bk = bk > 2047 ? 2047 : bk;
      sel = (bk >= T);
    }
    if (sel) {
      int p = atomicAdd(&s_cnt, 1);
      if (p < CAP) {
        int a = e / HW, hw = e - a * HW;
        u32 idx = (u32)(hw * 3 + a);
        keys[p] = ((u64)fmono(s) << 32) | (u32)(~idx);
      }
    }
  }
  __syncthreads();
  int cnt = s_cnt; if (cnt > CAP) cnt = CAP;
  // rank own keys (2 fast slots; slow path only if cnt>2048 — shouldn't happen)
  bool h0 = tid < cnt, h1 = tid + 1024 < cnt;
  u64 k0 = h0 ? keys[tid] : 0ull, k1 = h1 ? keys[tid + 1024] : 0ull;
  int r0 = 0, r1 = 0;
  int j = 0;
  for (; j + 3 < cnt; j += 4) {
    u64 a = keys[j], b = keys[j + 1], c = keys[j + 2], d = keys[j + 3];
    r0 += (int)(a > k0) + (int)(b > k0) + (int)(c > k0) + (int)(d > k0);
    r1 += (int)(a > k1) + (int)(b > k1) + (int)(c > k1) + (int)(d > k1);
  }
  for (; j < cnt; ++j) { u64 a = keys[j]; r0 += (int)(a > k0); r1 += (int)(a > k1); }
  if (h0 && r0 < k) {
    u32 idx = (~(u32)k0) & 0xFFFFFu;
    cs[r0] = fmono_inv((u32)(k0 >> 32));
    cp[r0] = ((u32)lvl << 20) | idx;
  }
  if (h1 && r1 < k) {
    u32 idx = (~(u32)k1) & 0xFFFFFu;
    cs[r1] = fmono_inv((u32)(k1 >> 32));
    cp[r1] = ((u32)lvl << 20) | idx;
  }
  if (cnt > 2048) {   // generic fallback, never expected with this data
    for (int p = tid + 2048; p < cnt; p += 1024) {
      u64 kp = keys[p]; int r = 0;
      for (int jj = 0; jj < cnt; ++jj) r += (int)(keys[jj] > kp);
      if (r < k) {
        u32 idx = (~(u32)kp) & 0xFFFFFu;
        cs[r] = fmono_inv((u32)(kp >> 32));
        cp[r] = ((u32)lvl << 20) | idx;
      }
    }
  }
}

// ---------------- kernel 2: decode boxes + post-validity sort keys ----------------
__global__ void k_decode(Ptrs P, const float* cand_score, const u32* cand_pos,
                         float4* boxes, u64* fkey) {
#pragma clang fp contract(off)
  int t = blockIdx.x * blockDim.x + threadIdx.x;
  if (t >= 2 * M_CAND) return;
  int img = t / M_CAND, slot = t - img * M_CAND;
  float s = cand_score[t];
  u32 pc = cand_pos[t];
  int lvl = (int)(pc >> 20), idx = (int)(pc & 0xFFFFFu);
  int W = d_dims[lvl], HW = W * W, stride = d_strides[lvl];
  int a = idx % 3, cell = idx / 3;
  int wx = cell % W, hy = cell / W;
  const float rr[3] = {0.5f, 1.0f, 2.0f};
  float sw = (float)(stride * 8);
  float wsz = sw * sqrtf(1.0f / rr[a]);
  float hsz = sw * sqrtf(rr[a]);
  float ax = (float)(wx * stride), ay = (float)(hy * stride);
  float a0 = ax + (-(wsz * 0.5f));
  float a1 = ay + (-(hsz * 0.5f));
  float a2 = ax + (wsz * 0.5f);
  float a3 = ay + (hsz * 0.5f);
  const float* rg = P.reg[lvl] + ((size_t)img * 12 + (size_t)(a * 4)) * HW + (size_t)hy * W + wx;
  float dx = rg[0], dy = rg[HW], dw = rg[2 * HW], dh = rg[3 * HW];
  const float MR = 4.135166556742356f;
  dw = fminf(fmaxf(dw, -MR), MR);
  dh = fminf(fmaxf(dh, -MR), MR);
  float px = (a0 + a2) * 0.5f, py = (a1 + a3) * 0.5f;
  float pw = a2 - a0, ph = a3 - a1;
  float gx = px + pw * dx;
  float gy = py + ph * dy;
  float gw = pw * expf(dw);
  float gh = ph * expf(dh);
  float fw = (float)(*P.iw), fh = (float)(*P.ih);
  float x1 = fminf(fmaxf(gx - gw * 0.5f, 0.0f), fw);
  float y1 = fminf(fmaxf(gy - gh * 0.5f, 0.0f), fh);
  float x2 = fminf(fmaxf(gx + gw * 0.5f, 0.0f), fw);
  float y2 = fminf(fmaxf(gy + gh * 0.5f, 0.0f), fh);
  boxes[t] = make_float4(x1, y1, x2, y2);
  if (!((x2 - x1 > 0.0f) && (y2 - y1 > 0.0f))) s = -1.0f;
  fkey[t] = ((u64)fmono(s) << 32) | (u32)(~(u32)slot);
}

// ---------------- kernel 3: global rank (count-of-greater) + scatter ----------------
__global__ __launch_bounds__(1024) void k_rank(const u64* fkey, const float4* boxes,
                                               float4* sboxes, float* sscore) {
  __shared__ u64 lk[M_CAND];   // 55.7 KB
  const int img = blockIdx.y, tid = threadIdx.x;
  const u64* K = fkey + (size_t)img * M_CAND;
  for (int j = tid; j < M_CAND; j += 1024) lk[j] = K[j];
  __syncthreads();
  int p = blockIdx.x * 1024 + tid;
  if (p >= M_CAND) return;
  u64 mk = lk[p];
  int r = 0, j = 0;
  for (; j + 3 < M_CAND; j += 4) {
    u64 a = lk[j], b = lk[j + 1], c = lk[j + 2], d = lk[j + 3];
    r += (int)(a > mk) + (int)(b > mk) + (int)(c > mk) + (int)(d > mk);
  }
  for (; j < M_CAND; ++j) r += (int)(lk[j] > mk);
  sboxes[(size_t)img * M_CAND + r] = boxes[(size_t)img * M_CAND + p];
  sscore[(size_t)img * M_CAND + r] = fmono_inv((u32)(mk >> 32));
}

// ---------------- kernel 4: suppression bitmask ----------------
__global__ __launch_bounds__(256) void k_mask(const float4* sboxes, u64* mask) {
#pragma clang fp contract(off)
  const int img = blockIdx.x / NW;
  const int rg = blockIdx.x % NW;
  const int tid = threadIdx.x;
  const int r = tid >> 2, q = tid & 3;
  const int i = (rg << 6) + r;
  const float4* BB = sboxes + (size_t)img * M_CAND;
  float4 bi = make_float4(0.f, 0.f, 0.f, 0.f);
  if (i < M_CAND) bi = BB[i];
  float areaI = (bi.z - bi.x) * (bi.w - bi.y);
  __shared__ float4 tj[256];
  __shared__ float ta[256];
  const int ntiles = (M_CAND + 255) >> 8;  // 28
  for (int jt = rg >> 2; jt < ntiles; ++jt) {
    __syncthreads();
    int j0 = (jt << 8) + tid;
    float4 bj = make_float4(0.f, 0.f, 0.f, 0.f);
    if (j0 < M_CAND) bj = BB[j0];
    tj[tid] = bj;
    ta[tid] = (bj.z - bj.x) * (bj.w - bj.y);
    __syncthreads();
    if (i < M_CAND) {
      u64 bits = 0ull;
      int jbase = (jt << 8) + (q << 6);
      for (int b = 0; b < 64; ++b) {
        float4 bb = tj[(q << 6) + b];
        float aj = ta[(q << 6) + b];
        float ltx = fmaxf(bi.x, bb.x), lty = fmaxf(bi.y, bb.y);
        float rbx = fminf(bi.z, bb.z), rby = fminf(bi.w, bb.w);
        float ww = fmaxf(rbx - ltx, 0.0f), hh = fmaxf(rby - lty, 0.0f);
        float inter = ww * hh;
        float uni = (areaI + aj) - inter;
        float iou = inter / fmaxf(uni, 1e-9f);
        int jj = jbase + b;
        bits |= ((u64)(iou > 0.7f && jj > i && jj < M_CAND)) << b;
      }
      mask[((size_t)img * M_CAND + i) * MW + (size_t)((jt << 2) + q)] = bits;
    }
  }
}

// ---------------- kernel 5: block-parallel greedy NMS scan + output ----------------
__global__ __launch_bounds__(256) void k_scan(const float4* sboxes, const float* sscore,
                                              const u64* mask, float* out) {
  const int img = blockIdx.x;
  const int tid = threadIdx.x;
  const float4* BB = sboxes + (size_t)img * M_CAND;
  const float* SS = sscore + (size_t)img * M_CAND;
  const u64* MK = mask + (size_t)img * M_CAND * MW;

  __shared__ u64 rem[NW];      // removed bit-vector
  __shared__ int s_krows[64];  // kept row indices of current group
  __shared__ int s_info[3];    // total, stop, nk

  for (int w0 = tid; w0 < NW; w0 += 256) rem[w0] = 0ull;
  if (tid == 0) { s_info[0] = 0; s_info[1] = 0; s_info[2] = 0; }
  __syncthreads();

  // preload group 0 row-words + scores (wave 0)
  u64 myw = 0ull; float si = -1.0f;
  if (tid < 64) {
    myw = MK[(size_t)tid * MW];   // g=0, i=tid < M always
    si = SS[tid];
  }

  for (int g = 0; g < NW; ++g) {
    if (tid < 64) {
      int i = (g << 6) + tid;
      u64 validm = __ballot(si > 0.0f);
      u64 rg = rem[g] | ~validm;
      u64 keptm = 0ull;
      u64 todo = ~rg;
      while (todo) {
        int l = __ffsll(todo) - 1;
        keptm |= (1ull << l);
        rg |= readlane64(myw, l);
        todo = ~rg;
        todo = (l < 63) ? (todo & (~0ull << (l + 1))) : 0ull;
      }
      int ntot = s_info[0];
      bool kept = (keptm >> tid) & 1ull;
      if (kept) {
        int below = __popcll(keptm & ((1ull << tid) - 1ull));
        int pos = ntot + below;
        if (pos < 1000) {
          float4 bx = BB[i];
          float* ob = out + ((size_t)img * 1000 + pos) * 4;
          ob[0] = bx.x; ob[1] = bx.y; ob[2] = bx.z; ob[3] = bx.w;
          out[8000 + img * 1000 + pos] = si;
          out[12000 + img * 1000 + pos] = 1.0f;
        }
        s_krows[below] = i;
      }
      if (tid == 0) {
        int nk = __popcll(keptm);
        int t2 = ntot + nk;
        s_info[0] = t2;
        s_info[1] = (t2 >= 1000) || (validm == 0ull);
        s_info[2] = nk;
      }
    }
    __syncthreads();
    if (s_info[1]) break;          // uniform
    int nk = s_info[2];
    // prefetch next group (independent of OR phase) to hide latency
    if (tid < 64 && g + 1 < NW) {
      int i = ((g + 1) << 6) + tid;
      myw = (i < M_CAND) ? MK[(size_t)i * MW + (g + 1)] : 0ull;
      si  = (i < M_CAND) ? SS[i] : -1.0f;
    }
    if (nk > 0 && g + 1 < NW) {
      int nw = NW - 1 - g;
      for (int wo = tid; wo < nw; wo += 256) {
        int w = g + 1 + wo;
        u64 acc = rem[w];
        int ki = 0;
        for (; ki + 3 < nk; ki += 4) {
          size_t q0 = (size_t)s_krows[ki] * MW + w;
          size_t q1 = (size_t)s_krows[ki + 1] * MW + w;
          size_t q2 = (size_t)s_krows[ki + 2] * MW + w;
          size_t q3 = (size_t)s_krows[ki + 3] * MW + w;
          u64 a0 = MK[q0], a1 = MK[q1], a2 = MK[q2], a3 = MK[q3];
          acc |= a0 | a1 | a2 | a3;
        }
        for (; ki < nk; ++ki) acc |= MK[(size_t)s_krows[ki] * MW + w];
        rem[w] = acc;
      }
    }
    __syncthreads();
  }

  int total = s_info[0];
  int filled = total < 1000 ? total : 1000;
  for (int p = filled + tid; p < 1000; p += 256) {
    float* ob = out + ((size_t)img * 1000 + p) * 4;
    ob[0] = 0.0f; ob[1] = 0.0f; ob[2] = 0.0f; ob[3] = 0.0f;
    out[8000 + img * 1000 + p] = 0.0f;
    out[12000 + img * 1000 + p] = 0.0f;
  }
  for (int p = tid; p < 1000; p += 256) out[10000 + img * 1000 + p] = 0.0f;  // labels
}

extern "C" void kernel_launch(void* const* d_in, const int* in_sizes, int n_in,
                              void* d_out, int out_size, void* d_ws, size_t ws_size,
                              hipStream_t stream) {
  Ptrs P;
  for (int i = 0; i < 5; ++i) {
    P.cls[i] = (const float*)d_in[2 * i];
    P.reg[i] = (const float*)d_in[2 * i + 1];
  }
  P.ih = (const int*)d_in[10];
  P.iw = (const int*)d_in[11];

  char* w = (char*)d_ws;
  float4* boxes  = (float4*)(w + OFF_BOX);
  float4* sboxes = (float4*)(w + OFF_SBOX);
  float*  cscore = (float*)(w + OFF_CS);
  u32*    cpos   = (u32*)(w + OFF_CP);
  float*  sscore = (float*)(w + OFF_SS);
  u64*    fkey   = (u64*)(w + OFF_KEY);
  u64*    maskp  = (u64*)(w + OFF_MASK);
  float* out = (float*)d_out;

  hipLaunchKernelGGL(k_select, dim3(10), dim3(1024), 0, stream, P, cscore, cpos);
  hipLaunchKernelGGL(k_decode, dim3((2 * M_CAND + 255) / 256), dim3(256), 0, stream, P, cscore, cpos, boxes, fkey);
  hipLaunchKernelGGL(k_rank, dim3(7, 2), dim3(1024), 0, stream, fkey, boxes, sboxes, sscore);
  hipLaunchKernelGGL(k_mask, dim3(2 * NW), dim3(256), 0, stream, sboxes, maskp);
  hipLaunchKernelGGL(k_scan, dim3(2), dim3(256), 0, stream, sboxes, sscore, maskp, out);
}

// Round 3
// 440.095 us; speedup vs baseline: 1.5194x; 1.3774x over previous
//
#include <hip/hip_runtime.h>
#include <math.h>

typedef unsigned long long u64;
typedef unsigned int u32;

#define M_CAND 6960
#define MW 112        // mask row stride in u64 words
#define NW 109
#define CAP 4096      // k_select reference-key capacity
#define MYC 384       // k_select per-chunk own-key capacity

// ws layout (bytes)
#define OFF_BOX   0u          // float4 [2][6960]
#define OFF_SBOX  222720u     // float4 [2][6960]
#define OFF_CS    445440u     // float [2][6960] cand_score; later aliased as comp_idx (int)
#define OFF_CP    501120u     // u32   [2][6960]
#define OFF_SS    556800u     // float [2][6960]
#define OFF_KEY   612480u     // u64   [2][6960]
#define OFF_VK    723840u     // u64   [2][6960] valid-compacted keys per level
#define OFF_VC    835200u     // int   [2][8]
#define OFF_MASK  835328u     // u64   [2][6960][112]

__device__ __forceinline__ u32 fmono(float f) {
  u32 u = __float_as_uint(f);
  return (u & 0x80000000u) ? ~u : (u | 0x80000000u);
}
__device__ __forceinline__ float fmono_inv(u32 m) {
  u32 u = (m & 0x80000000u) ? (m & 0x7FFFFFFFu) : ~m;
  return __uint_as_float(u);
}
__device__ __forceinline__ u64 readlane64(u64 v, int l) {
  u32 lo = (u32)__builtin_amdgcn_readlane((int)(u32)v, l);
  u32 hi = (u32)__builtin_amdgcn_readlane((int)(u32)(v >> 32), l);
  return ((u64)hi << 32) | lo;
}

struct Ptrs { const float* cls[5]; const float* reg[5]; const int* ih; const int* iw; };

__device__ const int d_dims[5]    = {128, 64, 32, 16, 8};
__device__ const int d_strides[5] = {8, 16, 32, 64, 128};
__device__ const int d_kvals[5]   = {2000, 2000, 2000, 768, 192};
__device__ const int d_segoff[5]  = {0, 2000, 4000, 6000, 6768};
__device__ const int d_logHW[5]   = {14, 12, 10, 8, 6};
__device__ const int d_blvl[28]   = {0,0,0,0,0,0,0,0, 1,1,1,1,1,1,1,1, 2,2,2,2,2,2,2,2, 3,3,3, 4};
__device__ const int d_bchunk[28] = {0,1,2,3,4,5,6,7, 0,1,2,3,4,5,6,7, 0,1,2,3,4,5,6,7, 0,1,2, 0};
__device__ const int d_nch[5]     = {8, 8, 8, 3, 1};

// ---------------- kernel 1: per-level sigmoid + exact top-k (chunked ranking) ----------------
__global__ __launch_bounds__(256) void k_select(Ptrs P, float* cand_score, u32* cand_pos) {
  const int bb = blockIdx.x, img = blockIdx.y;
  const int lvl = d_blvl[bb], chunk = d_bchunk[bb], nch = d_nch[lvl];
  const int lhw = d_logHW[lvl];
  const int HW = 1 << lhw, n = HW * 3;
  const int k = d_kvals[lvl], off = d_segoff[lvl];
  const float* cls = P.cls[lvl] + (size_t)img * 3 * HW;
  float* cs = cand_score + img * M_CAND + off;
  u32*   cp = cand_pos   + img * M_CAND + off;
  const int tid = threadIdx.x;

  __shared__ u32 hist[2048];
  __shared__ __align__(16) u64 keys[CAP];
  __shared__ u64 mykey[MYC];
  __shared__ int s_T, s_cnt, s_my;

  if (n > k) {
    for (int b = tid; b < 2048; b += 256) hist[b] = 0;
    __syncthreads();
    for (int e = tid; e < n; e += 256) {
      float s = 1.0f / (1.0f + expf(-cls[e]));
      int bk = (int)(s * 2048.0f); bk = bk > 2047 ? 2047 : bk;
      atomicAdd(&hist[bk], 1u);
    }
    __syncthreads();
    if (tid < 64) {   // wave 0: parallel suffix over 64 superbins of 32
      u32 part = 0;
      for (int j = 0; j < 32; ++j) part += hist[tid * 32 + ((j + tid) & 31)];
      u32 ss = part;
      for (int d = 1; d < 64; d <<= 1) {
        u32 o = __shfl_down(ss, d);
        if (tid + d < 64) ss += o;
      }
      u64 m = __ballot(ss >= (u32)k);
      int SB = 63 - __clzll(m);
      if (tid == SB) {
        u32 acc = ss - part;
        int Tloc = SB * 32;
        for (int b = SB * 32 + 31; b >= SB * 32; --b) {
          acc += hist[b];
          if (acc >= (u32)k) { Tloc = b; break; }
        }
        s_T = Tloc;
      }
    }
  } else if (tid == 0) s_T = 0;
  if (tid == 0) { s_cnt = 0; s_my = 0; }
  __syncthreads();
  const int T = s_T;
  const int per = (n + nch - 1) / nch;
  const int e0 = chunk * per, e1 = n < e0 + per ? n : e0 + per;
  for (int e = tid; e < n; e += 256) {
    float s = 1.0f / (1.0f + expf(-cls[e]));
    int bk = (int)(s * 2048.0f); bk = bk > 2047 ? 2047 : bk;
    if (bk >= T) {
      int a = e >> lhw, hw = e & (HW - 1);
      u32 it = (u32)(hw * 3 + a);                    // transposed index = JAX tie-break order
      u64 key = ((u64)fmono(s) << 32) | (u32)(~it);
      int p = atomicAdd(&s_cnt, 1);
      if (p < CAP) keys[p] = key;
      if (e >= e0 && e < e1) {
        int q = atomicAdd(&s_my, 1);
        if (q < MYC) mykey[q] = key;
      }
    }
  }
  __syncthreads();
  int cnt = s_cnt < CAP ? s_cnt : CAP;
  int my  = s_my  < MYC ? s_my  : MYC;
  if (tid == 0 && cnt < CAP && (cnt & 1)) keys[cnt] = 0ull;
  __syncthreads();
  int cntr = (cnt + 1) & ~1; if (cntr > CAP) cntr = CAP;
  for (int p = tid; p < my; p += 256) {
    u64 mk = mykey[p];
    int r = 0;
    for (int j = 0; j < cntr; j += 2) {
      ulonglong2 kk = *(const ulonglong2*)&keys[j];
      r += (int)(kk.x > mk) + (int)(kk.y > mk);
    }
    if (r < k) {
      u32 it = ~(u32)mk;
      cs[r] = fmono_inv((u32)(mk >> 32));
      cp[r] = ((u32)lvl << 20) | (it & 0xFFFFFu);
    }
  }
}

// ---------------- kernel 2: decode boxes + keys (invalid -> score -1) ----------------
__global__ __launch_bounds__(256) void k_decode(Ptrs P, const float* cand_score, const u32* cand_pos,
                                                float4* boxes, u64* fkey) {
#pragma clang fp contract(off)
  int t = blockIdx.x * 256 + threadIdx.x;
  if (t >= 2 * M_CAND) return;
  int img = t / M_CAND, slot = t - img * M_CAND;
  float s = cand_score[t];
  u32 pc = cand_pos[t];
  int lvl = (int)(pc >> 20), idx = (int)(pc & 0xFFFFFu);
  int W = d_dims[lvl], HW = W * W, stride = d_strides[lvl];
  int a = idx % 3, cell = idx / 3;
  int wx = cell % W, hy = cell / W;
  const float rr[3] = {0.5f, 1.0f, 2.0f};
  float sw = (float)(stride * 8);
  float wsz = sw * sqrtf(1.0f / rr[a]);
  float hsz = sw * sqrtf(rr[a]);
  float ax = (float)(wx * stride), ay = (float)(hy * stride);
  float a0 = ax + (-(wsz * 0.5f));
  float a1 = ay + (-(hsz * 0.5f));
  float a2 = ax + (wsz * 0.5f);
  float a3 = ay + (hsz * 0.5f);
  const float* rg = P.reg[lvl] + ((size_t)img * 12 + (size_t)(a * 4)) * HW + (size_t)hy * W + wx;
  float dx = rg[0], dy = rg[HW], dw = rg[2 * HW], dh = rg[3 * HW];
  const float MR = 4.135166556742356f;
  dw = fminf(fmaxf(dw, -MR), MR);
  dh = fminf(fmaxf(dh, -MR), MR);
  float px = (a0 + a2) * 0.5f, py = (a1 + a3) * 0.5f;
  float pw = a2 - a0, ph = a3 - a1;
  float gx = px + pw * dx;
  float gy = py + ph * dy;
  float gw = pw * expf(dw);
  float gh = ph * expf(dh);
  float fw = (float)(*P.iw), fh = (float)(*P.ih);
  float x1 = fminf(fmaxf(gx - gw * 0.5f, 0.0f), fw);
  float y1 = fminf(fmaxf(gy - gh * 0.5f, 0.0f), fh);
  float x2 = fminf(fmaxf(gx + gw * 0.5f, 0.0f), fw);
  float y2 = fminf(fmaxf(gy + gh * 0.5f, 0.0f), fh);
  boxes[t] = make_float4(x1, y1, x2, y2);
  if (!((x2 - x1 > 0.0f) && (y2 - y1 > 0.0f))) s = -1.0f;
  fkey[t] = ((u64)fmono(s) << 32) | (u32)(~(u32)slot);
}

// ---------------- kernel 3a: per-level stable valid-compaction (block scan) ----------------
__global__ __launch_bounds__(256) void k_compact(const u64* fkey, u64* vkeys, int* comp, int* vcnt) {
  const int lvl = blockIdx.x, img = blockIdx.y, tid = threadIdx.x;
  const int k = d_kvals[lvl], off = d_segoff[lvl];
  const u64* fk = fkey + (size_t)img * M_CAND + off;
  u64* vk = vkeys + (size_t)img * M_CAND + off;
  int* cm = comp + (size_t)img * M_CAND + off;
  __shared__ int wvt[4];
  __shared__ int s_vb;
  if (tid == 0) s_vb = 0;
  __syncthreads();
  const int lane = tid & 63, wid = tid >> 6;
  const u64 ltm = lane ? (~0ull >> (64 - lane)) : 0ull;
  for (int base = 0; base < k; base += 256) {
    int t = base + tid;
    bool act = t < k;
    u64 key = act ? fk[t] : 0ull;
    bool v = act && (key >> 63);
    u64 bal = __ballot(v);
    int pv = __popcll(bal & ltm);
    if (lane == 0) wvt[wid] = __popcll(bal);
    __syncthreads();
    int voff = 0;
    for (int w2 = 0; w2 < wid; ++w2) voff += wvt[w2];
    int vb = s_vb;
    if (act) {
      int nvb = vb + voff + pv;        // valids strictly before me (within level)
      if (v) { vk[nvb] = key; cm[t] = nvb; }
      else   { cm[t] = t - nvb; }      // invalids strictly before me
    }
    __syncthreads();
    if (tid == 0) s_vb = vb + wvt[0] + wvt[1] + wvt[2] + wvt[3];
    __syncthreads();
  }
  if (tid == 0) vcnt[img * 8 + lvl] = s_vb;
}

// ---------------- kernel 3b: global rank via 5-way merge (binary search) + scatter ----------------
__device__ __forceinline__ int count_greater(const u64* vk, int n, u64 key) {
  int lo = 0, hi = n;
  while (lo < hi) {
    int mid = (lo + hi) >> 1;
    if (vk[mid] > key) lo = mid + 1; else hi = mid;
  }
  return lo;
}

__global__ __launch_bounds__(256) void k_rank2(const u64* fkey, const u32* cand_pos,
                                               const int* comp, const int* vcnt,
                                               const u64* vkeys, const float4* boxes,
                                               float4* sboxes, float* sscore) {
  int t = blockIdx.x * 256 + threadIdx.x;
  if (t >= 2 * M_CAND) return;
  int img = t / M_CAND;
  u64 key = fkey[t];
  bool valid = (key >> 63) != 0;
  int lvl = (int)(cand_pos[t] >> 20);
  int vc[5];
  for (int l = 0; l < 5; ++l) vc[l] = vcnt[img * 8 + l];
  int r;
  if (valid) {
    r = comp[t];
    for (int l = 0; l < 5; ++l)
      if (l != lvl) r += count_greater(vkeys + (size_t)img * M_CAND + d_segoff[l], vc[l], key);
  } else {
    int NV = vc[0] + vc[1] + vc[2] + vc[3] + vc[4];
    int ib = 0;
    for (int l = 0; l < lvl; ++l) ib += d_kvals[l] - vc[l];
    r = NV + ib + comp[t];
  }
  sboxes[(size_t)img * M_CAND + r] = boxes[t];
  sscore[(size_t)img * M_CAND + r] = fmono_inv((u32)(key >> 32));
}

// ---------------- kernel 4: suppression bitmask (one word per thread) ----------------
__global__ __launch_bounds__(256) void k_mask(const float4* sboxes, u64* mask) {
#pragma clang fp contract(off)
  const int w = blockIdx.x, rc = blockIdx.y, img = blockIdx.z;
  if (rc * 4 > w) return;                 // only words w >= i>>6 are ever read
  const int tid = threadIdx.x;
  const float4* BB = sboxes + (size_t)img * M_CAND;
  const int jbase = w << 6;
  __shared__ float4 cb[64];
  __shared__ float ca[64];
  if (tid < 64) {
    int j = jbase + tid;
    float4 bj = (j < M_CAND) ? BB[j] : make_float4(0.f, 0.f, 0.f, 0.f);
    cb[tid] = bj;
    ca[tid] = (bj.z - bj.x) * (bj.w - bj.y);
  }
  __syncthreads();
  const int i = rc * 256 + tid;
  if (i >= M_CAND) return;
  float4 bi = BB[i];
  float areaI = (bi.z - bi.x) * (bi.w - bi.y);
  u64 bits = 0ull;
#pragma unroll 4
  for (int b = 0; b < 64; ++b) {
    float4 bb = cb[b];
    float aj = ca[b];
    float ltx = fmaxf(bi.x, bb.x), lty = fmaxf(bi.y, bb.y);
    float rbx = fminf(bi.z, bb.z), rby = fminf(bi.w, bb.w);
    float ww = fmaxf(rbx - ltx, 0.0f), hh = fmaxf(rby - lty, 0.0f);
    float inter = ww * hh;
    float uni = (areaI + aj) - inter;
    float iou = inter / fmaxf(uni, 1e-9f);
    int jj = jbase + b;
    bits |= ((u64)(iou > 0.7f && jj > i && jj < M_CAND)) << b;
  }
  mask[((size_t)img * M_CAND + i) * MW + w] = bits;
}

// ---------------- kernel 5: block-parallel greedy NMS scan + output ----------------
__global__ __launch_bounds__(256) void k_scan(const float4* sboxes, const float* sscore,
                                              const u64* mask, float* out) {
  const int img = blockIdx.x;
  const int tid = threadIdx.x;
  const float4* BB = sboxes + (size_t)img * M_CAND;
  const float* SS = sscore + (size_t)img * M_CAND;
  const u64* MK = mask + (size_t)img * M_CAND * MW;

  __shared__ u64 rem[NW];
  __shared__ int s_krows[64];
  __shared__ int s_info[3];    // total, stop, nk

  for (int w0 = tid; w0 < NW; w0 += 256) rem[w0] = 0ull;
  if (tid == 0) { s_info[0] = 0; s_info[1] = 0; s_info[2] = 0; }
  __syncthreads();

  u64 myw = 0ull; float si = -1.0f;
  if (tid < 64) {
    myw = MK[(size_t)tid * MW];
    si = SS[tid];
  }

  for (int g = 0; g < NW; ++g) {
    if (tid < 64) {
      int i = (g << 6) + tid;
      u64 validm = __ballot(si > 0.0f);
      u64 rg = rem[g] | ~validm;
      u64 keptm = 0ull;
      u64 todo = ~rg;
      while (todo) {
        int l = __ffsll(todo) - 1;
        keptm |= (1ull << l);
        rg |= readlane64(myw, l);
        todo = ~rg;
        todo = (l < 63) ? (todo & (~0ull << (l + 1))) : 0ull;
      }
      int ntot = s_info[0];
      bool kept = (keptm >> tid) & 1ull;
      if (kept) {
        int below = __popcll(keptm & ((1ull << tid) - 1ull));
        int pos = ntot + below;
        if (pos < 1000) {
          float4 bx = BB[i];
          float* ob = out + ((size_t)img * 1000 + pos) * 4;
          ob[0] = bx.x; ob[1] = bx.y; ob[2] = bx.z; ob[3] = bx.w;
          out[8000 + img * 1000 + pos] = si;
          out[12000 + img * 1000 + pos] = 1.0f;
        }
        s_krows[below] = i;
      }
      if (tid == 0) {
        int nk = __popcll(keptm);
        int t2 = ntot + nk;
        s_info[0] = t2;
        s_info[1] = (t2 >= 1000) || (validm == 0ull);
        s_info[2] = nk;
      }
    }
    __syncthreads();
    if (s_info[1]) break;
    int nk = s_info[2];
    if (tid < 64 && g + 1 < NW) {   // prefetch next group
      int i = ((g + 1) << 6) + tid;
      myw = (i < M_CAND) ? MK[(size_t)i * MW + (g + 1)] : 0ull;
      si  = (i < M_CAND) ? SS[i] : -1.0f;
    }
    if (nk > 0 && g + 1 < NW) {
      int nw = NW - 1 - g;
      for (int wo = tid; wo < nw; wo += 256) {
        int w = g + 1 + wo;
        u64 acc = rem[w];
        int ki = 0;
        for (; ki + 3 < nk; ki += 4) {
          u64 a0 = MK[(size_t)s_krows[ki] * MW + w];
          u64 a1 = MK[(size_t)s_krows[ki + 1] * MW + w];
          u64 a2 = MK[(size_t)s_krows[ki + 2] * MW + w];
          u64 a3 = MK[(size_t)s_krows[ki + 3] * MW + w];
          acc |= a0 | a1 | a2 | a3;
        }
        for (; ki < nk; ++ki) acc |= MK[(size_t)s_krows[ki] * MW + w];
        rem[w] = acc;
      }
    }
    __syncthreads();
  }

  int total = s_info[0];
  int filled = total < 1000 ? total : 1000;
  for (int p = filled + tid; p < 1000; p += 256) {
    float* ob = out + ((size_t)img * 1000 + p) * 4;
    ob[0] = 0.0f; ob[1] = 0.0f; ob[2] = 0.0f; ob[3] = 0.0f;
    out[8000 + img * 1000 + p] = 0.0f;
    out[12000 + img * 1000 + p] = 0.0f;
  }
  for (int p = tid; p < 1000; p += 256) out[10000 + img * 1000 + p] = 0.0f;
}

extern "C" void kernel_launch(void* const* d_in, const int* in_sizes, int n_in,
                              void* d_out, int out_size, void* d_ws, size_t ws_size,
                              hipStream_t stream) {
  Ptrs P;
  for (int i = 0; i < 5; ++i) {
    P.cls[i] = (const float*)d_in[2 * i];
    P.reg[i] = (const float*)d_in[2 * i + 1];
  }
  P.ih = (const int*)d_in[10];
  P.iw = (const int*)d_in[11];

  char* w = (char*)d_ws;
  float4* boxes  = (float4*)(w + OFF_BOX);
  float4* sboxes = (float4*)(w + OFF_SBOX);
  float*  cscore = (float*)(w + OFF_CS);
  int*    comp   = (int*)(w + OFF_CS);      // aliased: cand_score dead after k_decode
  u32*    cpos   = (u32*)(w + OFF_CP);
  float*  sscore = (float*)(w + OFF_SS);
  u64*    fkey   = (u64*)(w + OFF_KEY);
  u64*    vkeys  = (u64*)(w + OFF_VK);
  int*    vcnt   = (int*)(w + OFF_VC);
  u64*    maskp  = (u64*)(w + OFF_MASK);
  float* out = (float*)d_out;

  hipLaunchKernelGGL(k_select, dim3(28, 2), dim3(256), 0, stream, P, cscore, cpos);
  hipLaunchKernelGGL(k_decode, dim3((2 * M_CAND + 255) / 256), dim3(256), 0, stream, P, cscore, cpos, boxes, fkey);
  hipLaunchKernelGGL(k_compact, dim3(5, 2), dim3(256), 0, stream, fkey, vkeys, comp, vcnt);
  hipLaunchKernelGGL(k_rank2, dim3((2 * M_CAND + 255) / 256), dim3(256), 0, stream,
                     fkey, cpos, comp, vcnt, vkeys, boxes, sboxes, sscore);
  hipLaunchKernelGGL(k_mask, dim3(NW, 28, 2), dim3(256), 0, stream, sboxes, maskp);
  hipLaunchKernelGGL(k_scan, dim3(2), dim3(256), 0, stream, sboxes, sscore, maskp, out);
}

// Round 4
// 307.663 us; speedup vs baseline: 2.1735x; 1.4304x over previous
//
#include <hip/hip_runtime.h>
#include <math.h>

typedef unsigned long long u64;
typedef unsigned int u32;

#define M_CAND 6960
#define MW 112        // mask row stride in u64 words
#define NW 109
#define CAP 4096      // per-level selected-list capacity

// ws layout (bytes)
#define OFF_BOX   0u          // float4 [2][6960]
#define OFF_SBOX  222720u     // float4 [2][6960]
#define OFF_CS    445440u     // float [2][6960] cand_score; later aliased as comp_idx (int)
#define OFF_CP    501120u     // u32   [2][6960]
#define OFF_SS    556800u     // float [2][6960]
#define OFF_KEY   612480u     // u64   [2][6960]
#define OFF_VK    723840u     // u64   [2][6960]
#define OFF_VC    835200u     // int   [2][8]
#define OFF_MASK  835328u     // u64   [2][6960][112]
// selection scratch ALIASES the mask region (dead before k_mask writes):
#define OFF_GH    OFF_MASK            // u32 [10][2048] histograms
#define OFF_GC    (OFF_MASK + 81920u) // u32 [32]: [0..9]=counters, [16..25]=thresholds
#define OFF_GL    (OFF_MASK + 82048u) // u64 [10][4096] selected lists

__device__ __forceinline__ u32 fmono(float f) {
  u32 u = __float_as_uint(f);
  return (u & 0x80000000u) ? ~u : (u | 0x80000000u);
}
__device__ __forceinline__ float fmono_inv(u32 m) {
  u32 u = (m & 0x80000000u) ? (m & 0x7FFFFFFFu) : ~m;
  return __uint_as_float(u);
}
__device__ __forceinline__ u64 readlane64(u64 v, int l) {
  u32 lo = (u32)__builtin_amdgcn_readlane((int)(u32)v, l);
  u32 hi = (u32)__builtin_amdgcn_readlane((int)(u32)(v >> 32), l);
  return ((u64)hi << 32) | lo;
}

struct Ptrs { const float* cls[5]; const float* reg[5]; const int* ih; const int* iw; };

__device__ const int d_dims[5]    = {128, 64, 32, 16, 8};
__device__ const int d_strides[5] = {8, 16, 32, 64, 128};
__device__ const int d_kvals[5]   = {2000, 2000, 2000, 768, 192};
__device__ const int d_segoff[5]  = {0, 2000, 4000, 6000, 6768};
__device__ const int d_logHW[5]   = {14, 12, 10, 8, 6};
// k_hist: 16 chunk-blocks per image (levels 0-2 only)
__device__ const int d_hlvl[16]   = {0,0,0,0,0,0,0,0,0,0,0,0, 1,1,1, 2};
__device__ const int d_hchk[16]   = {0,1,2,3,4,5,6,7,8,9,10,11, 0,1,2, 0};
// k_cselect: 18 chunk-blocks per image (all levels)
__device__ const int d_slvl[18]   = {0,0,0,0,0,0,0,0,0,0,0,0, 1,1,1, 2, 3, 4};
__device__ const int d_schk[18]   = {0,1,2,3,4,5,6,7,8,9,10,11, 0,1,2, 0, 0, 0};

__device__ __forceinline__ float sigm(float x) { return 1.0f / (1.0f + expf(-x)); }
__device__ __forceinline__ int binof(float s) {
  int b = (int)(s * 2048.0f);
  return b > 2047 ? 2047 : b;
}

// ---------------- kernel 1a: chunked score histogram ----------------
__global__ __launch_bounds__(256) void k_hist(Ptrs P, u32* ghist) {
  const int bb = blockIdx.x, img = blockIdx.y, tid = threadIdx.x;
  const int lvl = d_hlvl[bb], c0 = d_hchk[bb] << 12;
  const int n = 3 << d_logHW[lvl];
  const int seg = img * 5 + lvl;
  const float* cls = P.cls[lvl] + (size_t)img * n;
  __shared__ u32 hist[2048];
  for (int b = tid; b < 2048; b += 256) hist[b] = 0;
  __syncthreads();
  const int end = (c0 + 4096 < n) ? c0 + 4096 : n;
  int e = c0 + tid;
  for (; e + 768 < end; e += 1024) {
    float x0 = cls[e], x1 = cls[e + 256], x2 = cls[e + 512], x3 = cls[e + 768];
    atomicAdd(&hist[binof(sigm(x0))], 1u);
    atomicAdd(&hist[binof(sigm(x1))], 1u);
    atomicAdd(&hist[binof(sigm(x2))], 1u);
    atomicAdd(&hist[binof(sigm(x3))], 1u);
  }
  for (; e < end; e += 256) atomicAdd(&hist[binof(sigm(cls[e]))], 1u);
  __syncthreads();
  for (int b = tid; b < 2048; b += 256) {
    u32 h = hist[b];
    if (h) atomicAdd(&ghist[seg * 2048 + b], h);
  }
}

// ---------------- kernel 1b: threshold per (img,lvl) ----------------
__global__ __launch_bounds__(64) void k_thresh(const u32* ghist, u32* gc) {
  const int lvl = blockIdx.x, img = blockIdx.y, seg = img * 5 + lvl;
  const int k = d_kvals[lvl];
  const int lane = threadIdx.x;
  const u32* h = ghist + seg * 2048;
  u32 part = 0;
  for (int j = 0; j < 32; ++j) part += h[lane * 32 + j];
  u32 ss = part;
  for (int d = 1; d < 64; d <<= 1) {
    u32 o = __shfl_down(ss, d);
    if (lane + d < 64) ss += o;
  }
  u64 m = __ballot(ss >= (u32)k);
  int SB = 63 - __clzll(m);
  if (lane == SB) {
    u32 acc = ss - part;
    int T = SB * 32;
    for (int b = SB * 32 + 31; b >= SB * 32; --b) {
      acc += h[b];
      if (acc >= (u32)k) { T = b; break; }
    }
    gc[16 + seg] = (u32)T;
  }
}

// ---------------- kernel 1c: chunked select + append to per-level list ----------------
__global__ __launch_bounds__(256) void k_cselect(Ptrs P, u32* gc, u64* glist) {
  const int bb = blockIdx.x, img = blockIdx.y, tid = threadIdx.x;
  const int lvl = d_slvl[bb], c0 = d_schk[bb] << 12;
  const int lhw = d_logHW[lvl];
  const int HW = 1 << lhw, n = 3 * HW;
  const int seg = img * 5 + lvl;
  const float* cls = P.cls[lvl] + (size_t)img * n;
  const int T = (int)gc[16 + seg];     // 0 for levels 3/4 -> select all
  __shared__ u64 sel[4096];
  __shared__ int s_cnt, s_base;
  if (tid == 0) s_cnt = 0;
  __syncthreads();
  const int end = (c0 + 4096 < n) ? c0 + 4096 : n;
  int e = c0 + tid;
  for (; e + 768 < end; e += 1024) {
    float x0 = cls[e], x1 = cls[e + 256], x2 = cls[e + 512], x3 = cls[e + 768];
    float s0 = sigm(x0), s1 = sigm(x1), s2 = sigm(x2), s3 = sigm(x3);
    int ee[4] = {e, e + 256, e + 512, e + 768};
    float svals[4] = {s0, s1, s2, s3};
    for (int q2 = 0; q2 < 4; ++q2) {
      float s = svals[q2];
      if (binof(s) >= T) {
        int eq = ee[q2];
        int a = eq >> lhw, hw = eq & (HW - 1);
        u32 it = (u32)(hw * 3 + a);
        int p = atomicAdd(&s_cnt, 1);
        if (p < 4096) sel[p] = ((u64)fmono(s) << 32) | (u32)(~it);
      }
    }
  }
  for (; e < end; e += 256) {
    float s = sigm(cls[e]);
    if (binof(s) >= T) {
      int a = e >> lhw, hw = e & (HW - 1);
      u32 it = (u32)(hw * 3 + a);
      int p = atomicAdd(&s_cnt, 1);
      if (p < 4096) sel[p] = ((u64)fmono(s) << 32) | (u32)(~it);
    }
  }
  __syncthreads();
  int cnt = s_cnt < 4096 ? s_cnt : 4096;
  if (tid == 0) s_base = (int)atomicAdd(&gc[seg], (u32)cnt);
  __syncthreads();
  int base = s_base;
  u64* gl = glist + (size_t)seg * CAP;
  for (int p = tid; p < cnt; p += 256) {
    int q = base + p;
    if (q < CAP) gl[q] = sel[p];
  }
}

// ---------------- kernel 1d: rank within level -> sorted top-k scatter ----------------
__global__ __launch_bounds__(256) void k_rankL(const u32* gc, const u64* glist,
                                               float* cand_score, u32* cand_pos) {
  const int lvl = blockIdx.y, img = blockIdx.z, tid = threadIdx.x;
  const int seg = img * 5 + lvl;
  int cnt = (int)gc[seg]; if (cnt > CAP) cnt = CAP;
  const int c0 = blockIdx.x << 8;
  if (c0 >= cnt) return;
  const int k = d_kvals[lvl], off = d_segoff[lvl];
  const u64* gl = glist + (size_t)seg * CAP;
  __shared__ __align__(16) u64 sh[CAP];
  const int cntr = (cnt + 1) & ~1;
  for (int j = tid; j < cntr; j += 256) sh[j] = (j < cnt) ? gl[j] : 0ull;
  __syncthreads();
  const int p = c0 + tid;
  if (p >= cnt) return;
  const u64 mk = sh[p];
  int r = 0;
  for (int j = 0; j < cntr; j += 2) {
    ulonglong2 kk = *(const ulonglong2*)&sh[j];
    r += (int)(kk.x > mk) + (int)(kk.y > mk);
  }
  if (r < k) {
    u32 it = ~(u32)mk;
    cand_score[img * M_CAND + off + r] = fmono_inv((u32)(mk >> 32));
    cand_pos[img * M_CAND + off + r] = ((u32)lvl << 20) | (it & 0xFFFFFu);
  }
}

// ---------------- kernel 2: decode boxes + keys (invalid -> score -1) ----------------
__global__ __launch_bounds__(256) void k_decode(Ptrs P, const float* cand_score, const u32* cand_pos,
                                                float4* boxes, u64* fkey) {
#pragma clang fp contract(off)
  int t = blockIdx.x * 256 + threadIdx.x;
  if (t >= 2 * M_CAND) return;
  int img = t / M_CAND, slot = t - img * M_CAND;
  float s = cand_score[t];
  u32 pc = cand_pos[t];
  int lvl = (int)(pc >> 20), idx = (int)(pc & 0xFFFFFu);
  int W = d_dims[lvl], HW = W * W, stride = d_strides[lvl];
  int a = idx % 3, cell = idx / 3;
  int wx = cell % W, hy = cell / W;
  const float rr[3] = {0.5f, 1.0f, 2.0f};
  float sw = (float)(stride * 8);
  float wsz = sw * sqrtf(1.0f / rr[a]);
  float hsz = sw * sqrtf(rr[a]);
  float ax = (float)(wx * stride), ay = (float)(hy * stride);
  float a0 = ax + (-(wsz * 0.5f));
  float a1 = ay + (-(hsz * 0.5f));
  float a2 = ax + (wsz * 0.5f);
  float a3 = ay + (hsz * 0.5f);
  const float* rg = P.reg[lvl] + ((size_t)img * 12 + (size_t)(a * 4)) * HW + (size_t)hy * W + wx;
  float dx = rg[0], dy = rg[HW], dw = rg[2 * HW], dh = rg[3 * HW];
  const float MR = 4.135166556742356f;
  dw = fminf(fmaxf(dw, -MR), MR);
  dh = fminf(fmaxf(dh, -MR), MR);
  float px = (a0 + a2) * 0.5f, py = (a1 + a3) * 0.5f;
  float pw = a2 - a0, ph = a3 - a1;
  float gx = px + pw * dx;
  float gy = py + ph * dy;
  float gw = pw * expf(dw);
  float gh = ph * expf(dh);
  float fw = (float)(*P.iw), fh = (float)(*P.ih);
  float x1 = fminf(fmaxf(gx - gw * 0.5f, 0.0f), fw);
  float y1 = fminf(fmaxf(gy - gh * 0.5f, 0.0f), fh);
  float x2 = fminf(fmaxf(gx + gw * 0.5f, 0.0f), fw);
  float y2 = fminf(fmaxf(gy + gh * 0.5f, 0.0f), fh);
  boxes[t] = make_float4(x1, y1, x2, y2);
  if (!((x2 - x1 > 0.0f) && (y2 - y1 > 0.0f))) s = -1.0f;
  fkey[t] = ((u64)fmono(s) << 32) | (u32)(~(u32)slot);
}

// ---------------- kernel 3a: per-level stable valid-compaction ----------------
__global__ __launch_bounds__(256) void k_compact(const u64* fkey, u64* vkeys, int* comp, int* vcnt) {
  const int lvl = blockIdx.x, img = blockIdx.y, tid = threadIdx.x;
  const int k = d_kvals[lvl], off = d_segoff[lvl];
  const u64* fk = fkey + (size_t)img * M_CAND + off;
  u64* vk = vkeys + (size_t)img * M_CAND + off;
  int* cm = comp + (size_t)img * M_CAND + off;
  __shared__ int wvt[4];
  __shared__ int s_vb;
  if (tid == 0) s_vb = 0;
  __syncthreads();
  const int lane = tid & 63, wid = tid >> 6;
  const u64 ltm = lane ? (~0ull >> (64 - lane)) : 0ull;
  for (int base = 0; base < k; base += 256) {
    int t = base + tid;
    bool act = t < k;
    u64 key = act ? fk[t] : 0ull;
    bool v = act && (key >> 63);
    u64 bal = __ballot(v);
    int pv = __popcll(bal & ltm);
    if (lane == 0) wvt[wid] = __popcll(bal);
    __syncthreads();
    int voff = 0;
    for (int w2 = 0; w2 < wid; ++w2) voff += wvt[w2];
    int vb = s_vb;
    if (act) {
      int nvb = vb + voff + pv;
      if (v) { vk[nvb] = key; cm[t] = nvb; }
      else   { cm[t] = t - nvb; }
    }
    __syncthreads();
    if (tid == 0) s_vb = vb + wvt[0] + wvt[1] + wvt[2] + wvt[3];
    __syncthreads();
  }
  if (tid == 0) vcnt[img * 8 + lvl] = s_vb;
}

// ---------------- kernel 3b: global rank via 5-way merge + scatter ----------------
__device__ __forceinline__ int count_greater(const u64* vk, int n, u64 key) {
  int lo = 0, hi = n;
  while (lo < hi) {
    int mid = (lo + hi) >> 1;
    if (vk[mid] > key) lo = mid + 1; else hi = mid;
  }
  return lo;
}

__global__ __launch_bounds__(256) void k_rank2(const u64* fkey, const u32* cand_pos,
                                               const int* comp, const int* vcnt,
                                               const u64* vkeys, const float4* boxes,
                                               float4* sboxes, float* sscore) {
  int t = blockIdx.x * 256 + threadIdx.x;
  if (t >= 2 * M_CAND) return;
  int img = t / M_CAND;
  u64 key = fkey[t];
  bool valid = (key >> 63) != 0;
  int lvl = (int)(cand_pos[t] >> 20);
  int vc[5];
  for (int l = 0; l < 5; ++l) vc[l] = vcnt[img * 8 + l];
  int r;
  if (valid) {
    r = comp[t];
    for (int l = 0; l < 5; ++l)
      if (l != lvl) r += count_greater(vkeys + (size_t)img * M_CAND + d_segoff[l], vc[l], key);
  } else {
    int NV = vc[0] + vc[1] + vc[2] + vc[3] + vc[4];
    int ib = 0;
    for (int l = 0; l < lvl; ++l) ib += d_kvals[l] - vc[l];
    r = NV + ib + comp[t];
  }
  sboxes[(size_t)img * M_CAND + r] = boxes[t];
  sscore[(size_t)img * M_CAND + r] = fmono_inv((u32)(key >> 32));
}

// ---------------- kernel 4: suppression bitmask (one word per thread) ----------------
__global__ __launch_bounds__(256) void k_mask(const float4* sboxes, u64* mask) {
#pragma clang fp contract(off)
  const int w = blockIdx.x, rc = blockIdx.y, img = blockIdx.z;
  if (rc * 4 > w) return;
  const int tid = threadIdx.x;
  const float4* BB = sboxes + (size_t)img * M_CAND;
  const int jbase = w << 6;
  __shared__ float4 cb[64];
  __shared__ float ca[64];
  if (tid < 64) {
    int j = jbase + tid;
    float4 bj = (j < M_CAND) ? BB[j] : make_float4(0.f, 0.f, 0.f, 0.f);
    cb[tid] = bj;
    ca[tid] = (bj.z - bj.x) * (bj.w - bj.y);
  }
  __syncthreads();
  const int i = rc * 256 + tid;
  if (i >= M_CAND) return;
  float4 bi = BB[i];
  float areaI = (bi.z - bi.x) * (bi.w - bi.y);
  u64 bits = 0ull;
#pragma unroll 4
  for (int b = 0; b < 64; ++b) {
    float4 bb = cb[b];
    float aj = ca[b];
    float ltx = fmaxf(bi.x, bb.x), lty = fmaxf(bi.y, bb.y);
    float rbx = fminf(bi.z, bb.z), rby = fminf(bi.w, bb.w);
    float ww = fmaxf(rbx - ltx, 0.0f), hh = fmaxf(rby - lty, 0.0f);
    float inter = ww * hh;
    float uni = (areaI + aj) - inter;
    float iou = inter / fmaxf(uni, 1e-9f);
    int jj = jbase + b;
    bits |= ((u64)(iou > 0.7f && jj > i && jj < M_CAND)) << b;
  }
  mask[((size_t)img * M_CAND + i) * MW + w] = bits;
}

// ---------------- kernel 5: block-parallel greedy NMS scan + output ----------------
__global__ __launch_bounds__(256) void k_scan(const float4* sboxes, const float* sscore,
                                              const u64* mask, float* out) {
  const int img = blockIdx.x;
  const int tid = threadIdx.x;
  const float4* BB = sboxes + (size_t)img * M_CAND;
  const float* SS = sscore + (size_t)img * M_CAND;
  const u64* MK = mask + (size_t)img * M_CAND * MW;

  __shared__ u64 rem[NW];
  __shared__ int s_krows[64];
  __shared__ int s_info[3];    // total, stop, nk

  for (int w0 = tid; w0 < NW; w0 += 256) rem[w0] = 0ull;
  if (tid == 0) { s_info[0] = 0; s_info[1] = 0; s_info[2] = 0; }
  __syncthreads();

  u64 myw = 0ull; float si = -1.0f;
  if (tid < 64) {
    myw = MK[(size_t)tid * MW];
    si = SS[tid];
  }

  for (int g = 0; g < NW; ++g) {
    if (tid < 64) {
      int i = (g << 6) + tid;
      u64 validm = __ballot(si > 0.0f);
      u64 rg = rem[g] | ~validm;
      u64 keptm = 0ull;
      u64 todo = ~rg;
      while (todo) {
        int l = __ffsll(todo) - 1;
        keptm |= (1ull << l);
        rg |= readlane64(myw, l);
        todo = ~rg;
        todo = (l < 63) ? (todo & (~0ull << (l + 1))) : 0ull;
      }
      int ntot = s_info[0];
      bool kept = (keptm >> tid) & 1ull;
      if (kept) {
        int below = __popcll(keptm & ((1ull << tid) - 1ull));
        int pos = ntot + below;
        if (pos < 1000) {
          float4 bx = BB[i];
          float* ob = out + ((size_t)img * 1000 + pos) * 4;
          ob[0] = bx.x; ob[1] = bx.y; ob[2] = bx.z; ob[3] = bx.w;
          out[8000 + img * 1000 + pos] = si;
          out[12000 + img * 1000 + pos] = 1.0f;
        }
        s_krows[below] = i;
      }
      if (tid == 0) {
        int nk = __popcll(keptm);
        int t2 = ntot + nk;
        s_info[0] = t2;
        s_info[1] = (t2 >= 1000) || (validm == 0ull);
        s_info[2] = nk;
      }
    }
    __syncthreads();
    if (s_info[1]) break;
    int nk = s_info[2];
    if (tid < 64 && g + 1 < NW) {   // prefetch next group
      int i = ((g + 1) << 6) + tid;
      myw = (i < M_CAND) ? MK[(size_t)i * MW + (g + 1)] : 0ull;
      si  = (i < M_CAND) ? SS[i] : -1.0f;
    }
    if (nk > 0 && g + 1 < NW) {
      int nw = NW - 1 - g;
      for (int wo = tid; wo < nw; wo += 256) {
        int w = g + 1 + wo;
        u64 acc = rem[w];
        int ki = 0;
        for (; ki + 3 < nk; ki += 4) {
          u64 a0 = MK[(size_t)s_krows[ki] * MW + w];
          u64 a1 = MK[(size_t)s_krows[ki + 1] * MW + w];
          u64 a2 = MK[(size_t)s_krows[ki + 2] * MW + w];
          u64 a3 = MK[(size_t)s_krows[ki + 3] * MW + w];
          acc |= a0 | a1 | a2 | a3;
        }
        for (; ki < nk; ++ki) acc |= MK[(size_t)s_krows[ki] * MW + w];
        rem[w] = acc;
      }
    }
    __syncthreads();
  }

  int total = s_info[0];
  int filled = total < 1000 ? total : 1000;
  for (int p = filled + tid; p < 1000; p += 256) {
    float* ob = out + ((size_t)img * 1000 + p) * 4;
    ob[0] = 0.0f; ob[1] = 0.0f; ob[2] = 0.0f; ob[3] = 0.0f;
    out[8000 + img * 1000 + p] = 0.0f;
    out[12000 + img * 1000 + p] = 0.0f;
  }
  for (int p = tid; p < 1000; p += 256) out[10000 + img * 1000 + p] = 0.0f;
}

extern "C" void kernel_launch(void* const* d_in, const int* in_sizes, int n_in,
                              void* d_out, int out_size, void* d_ws, size_t ws_size,
                              hipStream_t stream) {
  Ptrs P;
  for (int i = 0; i < 5; ++i) {
    P.cls[i] = (const float*)d_in[2 * i];
    P.reg[i] = (const float*)d_in[2 * i + 1];
  }
  P.ih = (const int*)d_in[10];
  P.iw = (const int*)d_in[11];

  char* w = (char*)d_ws;
  float4* boxes  = (float4*)(w + OFF_BOX);
  float4* sboxes = (float4*)(w + OFF_SBOX);
  float*  cscore = (float*)(w + OFF_CS);
  int*    comp   = (int*)(w + OFF_CS);      // aliased: cand_score dead after k_decode
  u32*    cpos   = (u32*)(w + OFF_CP);
  float*  sscore = (float*)(w + OFF_SS);
  u64*    fkey   = (u64*)(w + OFF_KEY);
  u64*    vkeys  = (u64*)(w + OFF_VK);
  int*    vcnt   = (int*)(w + OFF_VC);
  u32*    ghist  = (u32*)(w + OFF_GH);
  u32*    gc     = (u32*)(w + OFF_GC);
  u64*    glist  = (u64*)(w + OFF_GL);
  u64*    maskp  = (u64*)(w + OFF_MASK);
  float* out = (float*)d_out;

  // zero histograms + counters/thresholds (aliases mask region; mask written later)
  hipMemsetAsync(w + OFF_GH, 0, 81920 + 128, stream);
  hipLaunchKernelGGL(k_hist,    dim3(16, 2), dim3(256), 0, stream, P, ghist);
  hipLaunchKernelGGL(k_thresh,  dim3(3, 2),  dim3(64),  0, stream, ghist, gc);
  hipLaunchKernelGGL(k_cselect, dim3(18, 2), dim3(256), 0, stream, P, gc, glist);
  hipLaunchKernelGGL(k_rankL,   dim3(16, 5, 2), dim3(256), 0, stream, gc, glist, cscore, cpos);
  hipLaunchKernelGGL(k_decode,  dim3((2 * M_CAND + 255) / 256), dim3(256), 0, stream, P, cscore, cpos, boxes, fkey);
  hipLaunchKernelGGL(k_compact, dim3(5, 2), dim3(256), 0, stream, fkey, vkeys, comp, vcnt);
  hipLaunchKernelGGL(k_rank2,   dim3((2 * M_CAND + 255) / 256), dim3(256), 0, stream,
                     fkey, cpos, comp, vcnt, vkeys, boxes, sboxes, sscore);
  hipLaunchKernelGGL(k_mask,    dim3(NW, 28, 2), dim3(256), 0, stream, sboxes, maskp);
  hipLaunchKernelGGL(k_scan,    dim3(2), dim3(256), 0, stream, sboxes, sscore, maskp, out);
}